// Round 7
// baseline (190.895 us; speedup 1.0000x reference)
//
#include <hip/hip_runtime.h>
#include <math.h>

// ExplaiNN fused forward: B=128, N=300, L=600, K=19, C1=100, PS=7
// LC=582, LP=83, NC=2
// R23 config:
//   fills ~90us (harness re-poison of ws @ 74% HBM peak -- fixed cost)
//   kA RESTRUCTURED: grid 512=(b,quarter) x 448thr (7 waves). x[b] staged
//       ONCE per block in LDS (9.6KB, 1 sync), amortized over 28 lane-tasks;
//       x-window read as broadcast ds_read (IN-ORDER -> compiler can emit
//       partial lgkmcnt waits and overlap under FMAs). Theory v3: R18's
//       per-channel 46-s_load burst forces lgkmcnt(0) full drains (SMEM is
//       out-of-order; LLVM can't partial-wait it; 92-SGPR dbuf infeasible)
//       = ~18us unhidden stall. R20 (per-task LDS staging) failed on
//       per-task sync + unpack + occupancy cliff -- amortization fixes that.
//       FMA order R18-bit-exact (absmax 0.0). All 512 blocks co-resident.
//   Falsified: occupancy lift (R17 =), c-rotation desync (R19 v),
//       per-task LDS staging (R20 v), VMEM-taint pipeline (R22 v, compiler
//       chunked it at VGPR=48), 4-wave WGs, 6-wide tile, lane=b, fp16-MFMA.
//   kB/kC/kP: R16-exact. (R17 fence-fusion falsified: cross-XCD L2 wb.)
#define EPS_ 1e-5f

// ---------------------------------------------------------------------------
// kP: cw4[c][kq][n][0..3] float4 conv-weight pack for kA (20 blocks, ~2us).
// ---------------------------------------------------------------------------
__global__ __launch_bounds__(256) void kP(const float* __restrict__ conv_w,
                                          float* __restrict__ cw4) {
    const int cq = blockIdx.x;              // 0..19
    const int c  = cq / 5;
    const int kq = cq - c * 5;
    for (int n = threadIdx.x; n < 300; n += 256) {
        float4 v;
        const int k0 = 4 * kq;
        v.x = (k0 + 0 < 19) ? conv_w[n * 76 + c * 19 + k0 + 0] : 0.f;
        v.y = (k0 + 1 < 19) ? conv_w[n * 76 + c * 19 + k0 + 1] : 0.f;
        v.z = (k0 + 2 < 19) ? conv_w[n * 76 + c * 19 + k0 + 2] : 0.f;
        v.w = (k0 + 3 < 19) ? conv_w[n * 76 + c * 19 + k0 + 3] : 0.f;
        reinterpret_cast<float4*>(cw4)[(c * 5 + kq) * 300 + n] = v;
    }
}

// ---------------------------------------------------------------------------
// kA: conv1d(4ch,K=19) + bias + bn1 + exp + maxpool(7,7).
// R23: block=(b,quarter), 7 waves; stage x[b] to LDS once; wave w does tasks
// tau = quarter + 4*(7t+w), t<4 (tau 0..111, clamp>104 -> benign dup of task
// 104, identical values/addresses; 6.7% redundancy == R18's 112/105).
// Per task: 46 broadcast ds_read per channel (partial-lgkm overlappable),
// cw4 float4 weight loads, persistent acc[4p x 7q], R18-exact FMA order.
// ---------------------------------------------------------------------------
__global__ __launch_bounds__(448) void kA(
        const float* __restrict__ x,        // [128][4][600]
        const float* __restrict__ cw4,      // [4][5][300][4]
        const float* __restrict__ conv_b,
        const float* __restrict__ g1, const float* __restrict__ b1,
        const float* __restrict__ m1, const float* __restrict__ v1,
        float* __restrict__ pooled)         // [300][83][128]
{
    const int bq = blockIdx.x;              // b*4 + quarter
    const int b  = bq >> 2;
    const int qt = bq & 3;
    const int tid = threadIdx.x;

    __shared__ float sX[2400];              // x[b]: 4ch x 600, 9.6KB

    {   // coalesced float4 staging of x[b]
        const float4* xsrc = reinterpret_cast<const float4*>(x + b * 2400);
        float4* sX4 = reinterpret_cast<float4*>(sX);
        for (int i = tid; i < 600; i += 448) sX4[i] = xsrc[i];
    }
    __syncthreads();

    const int w    = __builtin_amdgcn_readfirstlane(tid >> 6);  // 0..6
    const int lane = tid & 63;
    const float4* w4 = reinterpret_cast<const float4*>(cw4);

    #pragma unroll 1
    for (int t = 0; t < 4; ++t) {
        const int tau = qt + 4 * (7 * t + w);       // 0..111
        const int tc  = (tau > 104) ? 104 : tau;    // dup task 104: benign
        const int ng  = tc / 21;
        const int pc  = tc - ng * 21;
        const int p0c = pc * 4;
        const int p0  = (p0c > 79) ? 79 : p0c;      // p=79 dup: same value
        const int n   = ng * 64 + lane;
        const int nc  = (n < 300) ? n : 299;

        float acc[28];
        #pragma unroll
        for (int i = 0; i < 28; ++i) acc[i] = 0.f;

        #pragma unroll 1
        for (int c = 0; c < 4; ++c) {
            // broadcast LDS reads (uniform addr, in-order, partial-waitable)
            const float* xc = sX + c * 600 + 7 * p0;
            float xw[46];
            #pragma unroll
            for (int j = 0; j < 46; ++j) xw[j] = xc[j];

            #pragma unroll
            for (int kq = 0; kq < 5; ++kq) {
                const float4 wv4 = w4[(c * 5 + kq) * 300 + nc];
                const int ni = (kq == 4) ? 3 : 4;           // k<19
                #pragma unroll
                for (int i = 0; i < ni; ++i) {
                    const int k = 4 * kq + i;
                    const float wvv = (i == 0) ? wv4.x : (i == 1) ? wv4.y
                                    : (i == 2) ? wv4.z : wv4.w;
                    #pragma unroll
                    for (int p = 0; p < 4; ++p)
                        #pragma unroll
                        for (int q = 0; q < 7; ++q)
                            acc[p * 7 + q] = fmaf(xw[7 * p + q + k], wvv,
                                                  acc[p * 7 + q]);
                }
            }
        }

        const float A1 = g1[nc] * rsqrtf(v1[nc] + EPS_);
        const float B1 = fmaf(A1, conv_b[nc] - m1[nc], b1[nc]);
        if (n < 300) {
            float* op = pooled + ((size_t)n * 83 + p0) * 128 + b;
            #pragma unroll
            for (int p = 0; p < 4; ++p) {
                float mx = -INFINITY;       // exp monotone: max before exp
                #pragma unroll
                for (int q = 0; q < 7; ++q)
                    mx = fmaxf(mx, fmaf(A1, acc[p * 7 + q], B1));
                op[p * 128] = __expf(mx);
            }
        }
    }
}

// ---------------------------------------------------------------------------
// kB: fc1(K=83) + bn2 + relu + fc2 partial.  R16-exact (~12us):
// block = (n, b-half, h-half), grid 1200 x 256 -> 4.7 waves/SIMD;
// sW[83][60] staging (8-way writes ~free, broadcast reads conflict-free);
// fc2 partials to sp; kC absorbs fc2b+bn3+relu.
// ---------------------------------------------------------------------------
__global__ __launch_bounds__(256) void kB(
        const float* __restrict__ pooled,   // [300][83][128]
        const float* __restrict__ fc1w,     // [300][100][83]
        const float* __restrict__ fc1b,     // [300][100]
        const float* __restrict__ g2, const float* __restrict__ b2,
        const float* __restrict__ m2, const float* __restrict__ v2,
        const float* __restrict__ fc2w,     // [300][100]
        float* __restrict__ sp)             // [2][300][128] fc2 partials
{
    __shared__ float sW[83 * 60];           // 19.9 KB
    __shared__ float sRed[4][64];
    const int id  = blockIdx.x;             // 0..1199
    const int n   = id >> 2;
    const int rem = id & 3;
    const int bh  = rem >> 1;
    const int hq  = rem & 1;                // h-half: h in [hq*50, hq*50+50)
    const int tid = threadIdx.x;

    {   // stage this h-half: coalesced reads; stride-60 writes (8-way, ~free)
        const float* src = fc1w + (size_t)n * 8300 + hq * 50 * 83;
        for (int i = tid; i < 4150; i += 256) {
            const int h = i / 83, p = i - h * 83;
            sW[p * 60 + h] = src[i];
        }
        for (int i = tid; i < 830; i += 256) {   // zero pad h'=50..59
            const int p = i / 10, h = 50 + (i - p * 10);
            sW[p * 60 + h] = 0.f;
        }
    }
    __syncthreads();

    const int lane = tid & 63;
    const int wv   = __builtin_amdgcn_readfirstlane(tid >> 6);  // 0..3
    const int h0   = wv * 13;               // local: 0,13,26,39
    const int nh   = (wv < 3) ? 13 : 11;    // 13*3+11 = 50
    const int bb   = bh * 64 + lane;

    const float* pp = pooled + (size_t)n * 83 * 128 + bb;

    float acc[13];
    #pragma unroll
    for (int j = 0; j < 13; ++j) acc[j] = 0.f;

    #pragma unroll 4
    for (int p = 0; p < 83; ++p) {
        const float pv = pp[p * 128];       // coalesced 256B
        const float* wrow = sW + p * 60 + h0;
        #pragma unroll
        for (int j = 0; j < 13; ++j)        // broadcast b32 reads
            acc[j] = fmaf(wrow[j], pv, acc[j]);
    }

    // bn2 + relu + fc2 partial over this wave's real h's (params uniform)
    const int hbase = n * 100 + hq * 50 + h0;
    float part = 0.f;
    for (int j = 0; j < nh; ++j) {
        const int hi = hbase + j;
        const float A2 = g2[hi] * rsqrtf(v2[hi] + EPS_);
        const float C2 = fmaf(A2, fc1b[hi] - m2[hi], b2[hi]);
        part = fmaf(fmaxf(fmaf(A2, acc[j], C2), 0.f), fc2w[hi], part);
    }
    sRed[wv][lane] = part;
    __syncthreads();

    if (tid < 64) {
        const float s = sRed[0][tid] + sRed[1][tid] + sRed[2][tid] + sRed[3][tid];
        sp[((size_t)hq * 300 + n) * 128 + bh * 64 + tid] = s;
    }
}

// ---------------------------------------------------------------------------
// kC: combine fc2 partials + fc2b + bn3 + relu, then final [300]x[2] matmul.
// ---------------------------------------------------------------------------
__global__ __launch_bounds__(64) void kC(
        const float* __restrict__ sp,       // [2][300][128]
        const float* __restrict__ fc2b,
        const float* __restrict__ g3, const float* __restrict__ b3,
        const float* __restrict__ m3, const float* __restrict__ v3,
        const float* __restrict__ fw,       // [2][300]
        const float* __restrict__ fb,
        float* __restrict__ out)            // [128][2]
{
    const int b = blockIdx.x, t = threadIdx.x;
    float a0 = 0.f, a1 = 0.f;
    for (int nn = t; nn < 300; nn += 64) {
        const float s = sp[nn * 128 + b] + sp[(300 + nn) * 128 + b] + fc2b[nn];
        const float A3 = g3[nn] * rsqrtf(v3[nn] + EPS_);
        const float z = fmaxf(fmaf(A3, s - m3[nn], b3[nn]), 0.f);
        a0 = fmaf(z, fw[nn], a0);
        a1 = fmaf(z, fw[300 + nn], a1);
    }
    #pragma unroll
    for (int off = 32; off > 0; off >>= 1) {
        a0 += __shfl_xor(a0, off, 64);
        a1 += __shfl_xor(a1, off, 64);
    }
    if (t == 0) {
        out[b * 2 + 0] = a0 + fb[0];
        out[b * 2 + 1] = a1 + fb[1];
    }
}

extern "C" void kernel_launch(void* const* d_in, const int* in_sizes, int n_in,
                              void* d_out, int out_size, void* d_ws, size_t ws_size,
                              hipStream_t stream) {
    const float* x      = (const float*)d_in[0];
    const float* conv_w = (const float*)d_in[1];
    const float* conv_b = (const float*)d_in[2];
    const float* g1 = (const float*)d_in[3];
    const float* b1 = (const float*)d_in[4];
    const float* m1 = (const float*)d_in[5];
    const float* v1 = (const float*)d_in[6];
    const float* fc1_w = (const float*)d_in[7];
    const float* fc1_b = (const float*)d_in[8];
    const float* g2 = (const float*)d_in[9];
    const float* b2 = (const float*)d_in[10];
    const float* m2 = (const float*)d_in[11];
    const float* v2 = (const float*)d_in[12];
    const float* fc2_w = (const float*)d_in[13];
    const float* fc2_b = (const float*)d_in[14];
    const float* g3 = (const float*)d_in[15];
    const float* b3 = (const float*)d_in[16];
    const float* m3 = (const float*)d_in[17];
    const float* v3 = (const float*)d_in[18];
    const float* fw = (const float*)d_in[19];
    const float* fb = (const float*)d_in[20];
    float* out = (float*)d_out;

    float* pooled = (float*)d_ws;                        // 300*83*128 = 3187200
    float* sp     = pooled + (size_t)300 * 83 * 128;     // 2*300*128  = 76800
    float* cw4    = sp + 76800;                          // 4*5*300*4  = 24000
    // total ws: ~13.2 MB

    kP<<<20, 256, 0, stream>>>(conv_w, cw4);
    kA<<<512, 448, 0, stream>>>(x, cw4, conv_b, g1, b1, m1, v1, pooled);
    kB<<<1200, 256, 0, stream>>>(pooled, fc1_w, fc1_b, g2, b2, m2, v2,
                                 fc2_w, sp);
    kC<<<128, 64, 0, stream>>>(sp, fc2_b, g3, b3, m3, v3, fw, fb, out);
}

// Round 8
// 188.240 us; speedup vs baseline: 1.0141x; 1.0141x over previous
//
#include <hip/hip_runtime.h>
#include <math.h>

// ExplaiNN fused forward: B=128, N=300, L=600, K=19, C1=100, PS=7
// LC=582, LP=83, NC=2
// R24 config:
//   fills ~90us (harness re-poison of ws @ 74% HBM peak -- fixed cost)
//   kA: R23's LDS-x structure with the XCD write-split REPAIRED.
//       R23 forensics: WRITE_SIZE 12.6->25.9MB because grid (b*4+qt) put
//       adjacent b (same 64B pooled line) on different XCD L2s (non-
//       coherent) -> 2x write-back + bouncing. R18's invariant was
//       blocks-per-b % 8 == 0 (XCD = f(task), not f(b)). R24: grid
//       (b,oct)=128x8, id=b*8+oct -> XCD=oct for every (n,p0) writer set.
//       7 waves x 2 tasks (tau = oct+8*(w+7t), bijective 0..111, clamp
//       >104 benign dup). x[b] staged once/block (9.6KB, 1 sync), window
//       via broadcast ds_read. 4 blocks/CU x 7 waves = 28 waves/CU.
//       Predict: WRITE ~12.6MB, occ >=60%, dur ~32us; if dur >=45 at high
//       occ -> kA plateau, revert R18.
//   kB/kC/kP: R16-exact. Falsified: R17 fence-fusion (cross-XCD wb),
//       occupancy-only lift (R17 =), c-rotation (R19 v), per-task LDS
//       (R20 v), VMEM-taint pipeline (R22 v), 4-wave WGs, 6-wide tile.
#define EPS_ 1e-5f

// ---------------------------------------------------------------------------
// kP: cw4[c][kq][n][0..3] float4 conv-weight pack for kA (20 blocks, ~2us).
// ---------------------------------------------------------------------------
__global__ __launch_bounds__(256) void kP(const float* __restrict__ conv_w,
                                          float* __restrict__ cw4) {
    const int cq = blockIdx.x;              // 0..19
    const int c  = cq / 5;
    const int kq = cq - c * 5;
    for (int n = threadIdx.x; n < 300; n += 256) {
        float4 v;
        const int k0 = 4 * kq;
        v.x = (k0 + 0 < 19) ? conv_w[n * 76 + c * 19 + k0 + 0] : 0.f;
        v.y = (k0 + 1 < 19) ? conv_w[n * 76 + c * 19 + k0 + 1] : 0.f;
        v.z = (k0 + 2 < 19) ? conv_w[n * 76 + c * 19 + k0 + 2] : 0.f;
        v.w = (k0 + 3 < 19) ? conv_w[n * 76 + c * 19 + k0 + 3] : 0.f;
        reinterpret_cast<float4*>(cw4)[(c * 5 + kq) * 300 + n] = v;
    }
}

// ---------------------------------------------------------------------------
// kA: conv1d(4ch,K=19) + bias + bn1 + exp + maxpool(7,7).
// R24: block=(b,oct) 128x8, 448 thr (7 waves). Stage x[b] in LDS once;
// wave w does tasks tau = oct + 8*(w + 7t), t<2 (bijective over 0..111;
// tau>104 -> dup of task 104, identical values/addresses). Per task:
// x-window from LDS broadcast ds_read, cw4 float4 weight loads,
// persistent acc[4p x 7q], R18-exact FMA order (absmax 0.0).
// blocks-per-b = 8 -> XCD = oct: all writers of a pooled 64B line share
// one XCD L2 (R18 invariant restored; R23 broke it -> 2x WRITE_SIZE).
// ---------------------------------------------------------------------------
__global__ __launch_bounds__(448) void kA(
        const float* __restrict__ x,        // [128][4][600]
        const float* __restrict__ cw4,      // [4][5][300][4]
        const float* __restrict__ conv_b,
        const float* __restrict__ g1, const float* __restrict__ b1,
        const float* __restrict__ m1, const float* __restrict__ v1,
        float* __restrict__ pooled)         // [300][83][128]
{
    const int id  = blockIdx.x;             // b*8 + oct
    const int b   = id >> 3;
    const int oct = id & 7;
    const int tid = threadIdx.x;

    __shared__ float sX[2400];              // x[b]: 4ch x 600, 9.6KB

    {   // coalesced float4 staging of x[b]
        const float4* xsrc = reinterpret_cast<const float4*>(x + b * 2400);
        float4* sX4 = reinterpret_cast<float4*>(sX);
        for (int i = tid; i < 600; i += 448) sX4[i] = xsrc[i];
    }
    __syncthreads();

    const int w    = __builtin_amdgcn_readfirstlane(tid >> 6);  // 0..6
    const int lane = tid & 63;
    const float4* w4 = reinterpret_cast<const float4*>(cw4);

    #pragma unroll 1
    for (int t = 0; t < 2; ++t) {
        const int tau = oct + 8 * (w + 7 * t);      // 0..111
        const int tc  = (tau > 104) ? 104 : tau;    // dup task 104: benign
        const int ng  = tc / 21;
        const int pc  = tc - ng * 21;
        const int p0c = pc * 4;
        const int p0  = (p0c > 79) ? 79 : p0c;      // p=79 dup: same value
        const int n   = ng * 64 + lane;
        const int nc  = (n < 300) ? n : 299;

        float acc[28];
        #pragma unroll
        for (int i = 0; i < 28; ++i) acc[i] = 0.f;

        #pragma unroll 1
        for (int c = 0; c < 4; ++c) {
            // broadcast LDS reads (uniform addr, in-order, partial-waitable)
            const float* xc = sX + c * 600 + 7 * p0;
            float xw[46];
            #pragma unroll
            for (int j = 0; j < 46; ++j) xw[j] = xc[j];

            #pragma unroll
            for (int kq = 0; kq < 5; ++kq) {
                const float4 wv4 = w4[(c * 5 + kq) * 300 + nc];
                const int ni = (kq == 4) ? 3 : 4;           // k<19
                #pragma unroll
                for (int i = 0; i < ni; ++i) {
                    const int k = 4 * kq + i;
                    const float wvv = (i == 0) ? wv4.x : (i == 1) ? wv4.y
                                    : (i == 2) ? wv4.z : wv4.w;
                    #pragma unroll
                    for (int p = 0; p < 4; ++p)
                        #pragma unroll
                        for (int q = 0; q < 7; ++q)
                            acc[p * 7 + q] = fmaf(xw[7 * p + q + k], wvv,
                                                  acc[p * 7 + q]);
                }
            }
        }

        const float A1 = g1[nc] * rsqrtf(v1[nc] + EPS_);
        const float B1 = fmaf(A1, conv_b[nc] - m1[nc], b1[nc]);
        if (n < 300) {
            float* op = pooled + ((size_t)n * 83 + p0) * 128 + b;
            #pragma unroll
            for (int p = 0; p < 4; ++p) {
                float mx = -INFINITY;       // exp monotone: max before exp
                #pragma unroll
                for (int q = 0; q < 7; ++q)
                    mx = fmaxf(mx, fmaf(A1, acc[p * 7 + q], B1));
                op[p * 128] = __expf(mx);
            }
        }
    }
}

// ---------------------------------------------------------------------------
// kB: fc1(K=83) + bn2 + relu + fc2 partial.  R16-exact (~12us):
// block = (n, b-half, h-half), grid 1200 x 256 -> 4.7 waves/SIMD;
// sW[83][60] staging (8-way writes ~free, broadcast reads conflict-free);
// fc2 partials to sp; kC absorbs fc2b+bn3+relu.
// ---------------------------------------------------------------------------
__global__ __launch_bounds__(256) void kB(
        const float* __restrict__ pooled,   // [300][83][128]
        const float* __restrict__ fc1w,     // [300][100][83]
        const float* __restrict__ fc1b,     // [300][100]
        const float* __restrict__ g2, const float* __restrict__ b2,
        const float* __restrict__ m2, const float* __restrict__ v2,
        const float* __restrict__ fc2w,     // [300][100]
        float* __restrict__ sp)             // [2][300][128] fc2 partials
{
    __shared__ float sW[83 * 60];           // 19.9 KB
    __shared__ float sRed[4][64];
    const int id  = blockIdx.x;             // 0..1199
    const int n   = id >> 2;
    const int rem = id & 3;
    const int bh  = rem >> 1;
    const int hq  = rem & 1;                // h-half: h in [hq*50, hq*50+50)
    const int tid = threadIdx.x;

    {   // stage this h-half: coalesced reads; stride-60 writes (8-way, ~free)
        const float* src = fc1w + (size_t)n * 8300 + hq * 50 * 83;
        for (int i = tid; i < 4150; i += 256) {
            const int h = i / 83, p = i - h * 83;
            sW[p * 60 + h] = src[i];
        }
        for (int i = tid; i < 830; i += 256) {   // zero pad h'=50..59
            const int p = i / 10, h = 50 + (i - p * 10);
            sW[p * 60 + h] = 0.f;
        }
    }
    __syncthreads();

    const int lane = tid & 63;
    const int wv   = __builtin_amdgcn_readfirstlane(tid >> 6);  // 0..3
    const int h0   = wv * 13;               // local: 0,13,26,39
    const int nh   = (wv < 3) ? 13 : 11;    // 13*3+11 = 50
    const int bb   = bh * 64 + lane;

    const float* pp = pooled + (size_t)n * 83 * 128 + bb;

    float acc[13];
    #pragma unroll
    for (int j = 0; j < 13; ++j) acc[j] = 0.f;

    #pragma unroll 4
    for (int p = 0; p < 83; ++p) {
        const float pv = pp[p * 128];       // coalesced 256B
        const float* wrow = sW + p * 60 + h0;
        #pragma unroll
        for (int j = 0; j < 13; ++j)        // broadcast b32 reads
            acc[j] = fmaf(wrow[j], pv, acc[j]);
    }

    // bn2 + relu + fc2 partial over this wave's real h's (params uniform)
    const int hbase = n * 100 + hq * 50 + h0;
    float part = 0.f;
    for (int j = 0; j < nh; ++j) {
        const int hi = hbase + j;
        const float A2 = g2[hi] * rsqrtf(v2[hi] + EPS_);
        const float C2 = fmaf(A2, fc1b[hi] - m2[hi], b2[hi]);
        part = fmaf(fmaxf(fmaf(A2, acc[j], C2), 0.f), fc2w[hi], part);
    }
    sRed[wv][lane] = part;
    __syncthreads();

    if (tid < 64) {
        const float s = sRed[0][tid] + sRed[1][tid] + sRed[2][tid] + sRed[3][tid];
        sp[((size_t)hq * 300 + n) * 128 + bh * 64 + tid] = s;
    }
}

// ---------------------------------------------------------------------------
// kC: combine fc2 partials + fc2b + bn3 + relu, then final [300]x[2] matmul.
// ---------------------------------------------------------------------------
__global__ __launch_bounds__(64) void kC(
        const float* __restrict__ sp,       // [2][300][128]
        const float* __restrict__ fc2b,
        const float* __restrict__ g3, const float* __restrict__ b3,
        const float* __restrict__ m3, const float* __restrict__ v3,
        const float* __restrict__ fw,       // [2][300]
        const float* __restrict__ fb,
        float* __restrict__ out)            // [128][2]
{
    const int b = blockIdx.x, t = threadIdx.x;
    float a0 = 0.f, a1 = 0.f;
    for (int nn = t; nn < 300; nn += 64) {
        const float s = sp[nn * 128 + b] + sp[(300 + nn) * 128 + b] + fc2b[nn];
        const float A3 = g3[nn] * rsqrtf(v3[nn] + EPS_);
        const float z = fmaxf(fmaf(A3, s - m3[nn], b3[nn]), 0.f);
        a0 = fmaf(z, fw[nn], a0);
        a1 = fmaf(z, fw[300 + nn], a1);
    }
    #pragma unroll
    for (int off = 32; off > 0; off >>= 1) {
        a0 += __shfl_xor(a0, off, 64);
        a1 += __shfl_xor(a1, off, 64);
    }
    if (t == 0) {
        out[b * 2 + 0] = a0 + fb[0];
        out[b * 2 + 1] = a1 + fb[1];
    }
}

extern "C" void kernel_launch(void* const* d_in, const int* in_sizes, int n_in,
                              void* d_out, int out_size, void* d_ws, size_t ws_size,
                              hipStream_t stream) {
    const float* x      = (const float*)d_in[0];
    const float* conv_w = (const float*)d_in[1];
    const float* conv_b = (const float*)d_in[2];
    const float* g1 = (const float*)d_in[3];
    const float* b1 = (const float*)d_in[4];
    const float* m1 = (const float*)d_in[5];
    const float* v1 = (const float*)d_in[6];
    const float* fc1_w = (const float*)d_in[7];
    const float* fc1_b = (const float*)d_in[8];
    const float* g2 = (const float*)d_in[9];
    const float* b2 = (const float*)d_in[10];
    const float* m2 = (const float*)d_in[11];
    const float* v2 = (const float*)d_in[12];
    const float* fc2_w = (const float*)d_in[13];
    const float* fc2_b = (const float*)d_in[14];
    const float* g3 = (const float*)d_in[15];
    const float* b3 = (const float*)d_in[16];
    const float* m3 = (const float*)d_in[17];
    const float* v3 = (const float*)d_in[18];
    const float* fw = (const float*)d_in[19];
    const float* fb = (const float*)d_in[20];
    float* out = (float*)d_out;

    float* pooled = (float*)d_ws;                        // 300*83*128 = 3187200
    float* sp     = pooled + (size_t)300 * 83 * 128;     // 2*300*128  = 76800
    float* cw4    = sp + 76800;                          // 4*5*300*4  = 24000
    // total ws: ~13.2 MB

    kP<<<20, 256, 0, stream>>>(conv_w, cw4);
    kA<<<128 * 8, 448, 0, stream>>>(x, cw4, conv_b, g1, b1, m1, v1, pooled);
    kB<<<1200, 256, 0, stream>>>(pooled, fc1_w, fc1_b, g2, b2, m2, v2,
                                 fc2_w, sp);
    kC<<<128, 64, 0, stream>>>(sp, fc2_b, g3, b3, m3, v3, fw, fb, out);
}

// Round 9
// 170.379 us; speedup vs baseline: 1.1204x; 1.1048x over previous
//
#include <hip/hip_runtime.h>
#include <math.h>

// ExplaiNN fused forward: B=128, N=300, L=600, K=19, C1=100, PS=7
// LC=582, LP=83, NC=2
// R25 config:
//   fills ~90us (harness re-poison, fixed 256MB poison -- its own roofline)
//   kA: R18-EXACT structure (best measured: 44.6-45.4us) + one-shot s_sleep
//       start-stagger (k=id%3 -> 0/~640/~1280cyc). Convoy theory, properly
//       tested this time: waves stall IN PHASE (3.3 waves x 56% busy never
//       fills the SIMD; R19's channel-ROTATION changed what loads, not WHEN
//       stalls hit; equal task lengths keep block generations sync'd).
//       A TIME offset is the only untested lever. Cost if wrong: <1us.
//   kB: unroll 4->8 on the 83-iter pv loop (4 in-flight loads cover ~100cy
//       of ~200cy L2 latency; 8 covers it). Per-acc FMA order unchanged.
//   kC/kP: R16-exact.
//   Falsified: R17 fence-fusion (cross-XCD wb), occupancy lift (R17 =),
//       c-rotation (R19 v), per-task LDS (R20 v), VMEM-taint (R22 v),
//       amortized LDS-x (R23/R24 v), 4-wave WGs, 6-wide tile, lane=b,
//       fp16-MFMA im2col, 7 latency interventions. XCD invariant: kA
//       blocks-per-b % 8 == 0 (R23 broke it -> 2x WRITE_SIZE; R24 fixed).
#define EPS_ 1e-5f

// ---------------------------------------------------------------------------
// kP: cw4[c][kq][n][0..3] float4 conv-weight pack for kA (20 blocks, ~2us).
// ---------------------------------------------------------------------------
__global__ __launch_bounds__(256) void kP(const float* __restrict__ conv_w,
                                          float* __restrict__ cw4) {
    const int cq = blockIdx.x;              // 0..19
    const int c  = cq / 5;
    const int kq = cq - c * 5;
    for (int n = threadIdx.x; n < 300; n += 256) {
        float4 v;
        const int k0 = 4 * kq;
        v.x = (k0 + 0 < 19) ? conv_w[n * 76 + c * 19 + k0 + 0] : 0.f;
        v.y = (k0 + 1 < 19) ? conv_w[n * 76 + c * 19 + k0 + 1] : 0.f;
        v.z = (k0 + 2 < 19) ? conv_w[n * 76 + c * 19 + k0 + 2] : 0.f;
        v.w = (k0 + 3 < 19) ? conv_w[n * 76 + c * 19 + k0 + 3] : 0.f;
        reinterpret_cast<float4*>(cw4)[(c * 5 + kq) * 300 + n] = v;
    }
}

// ---------------------------------------------------------------------------
// kA: conv1d(4ch,K=19) + bias + bn1 + exp + maxpool(7,7).
// R18-exact: 2 waves/WG (subs 2i, 2i+1), grid 128*56 x 128. Persistent
// acc[4p x 7q]; cw4 float4 weight loads; x window wave-uniform -> s_loads
// (46/channel = SGPR-budget max; compiler MUST burst per channel).
// R25 addition: one-shot s_sleep stagger (k = id%3) to anti-phase
// SIMD-mates' per-channel lgkm drains. 56%8==0 keeps XCD write locality.
// ---------------------------------------------------------------------------
__global__ __launch_bounds__(128) void kA(
        const float* __restrict__ x,        // [128][4][600]
        const float* __restrict__ cw4,      // [4][5][300][4]
        const float* __restrict__ conv_b,
        const float* __restrict__ g1, const float* __restrict__ b1,
        const float* __restrict__ m1, const float* __restrict__ v1,
        float* __restrict__ pooled)         // [300][83][128]
{
    const int id  = blockIdx.x;             // b*56 + i2
    const int b   = id / 56;
    const int i2  = id - b * 56;
    const int wv  = __builtin_amdgcn_readfirstlane(threadIdx.x >> 6); // 0..1
    const int sub = i2 * 2 + wv;            // 0..111
    if (sub >= 105) return;                 // wave-uniform exit
    const int ng  = sub / 21;
    const int pc  = sub - ng * 21;
    const int p0c = pc * 4;
    const int p0  = (p0c > 79) ? 79 : p0c;  // p=79 done twice, same value
    const int lane = threadIdx.x & 63;
    const int n   = ng * 64 + lane;
    const int nc  = (n < 300) ? n : 299;

    // R25: one-shot start-time stagger to break the stall convoy.
    // k = id % 3 is coprime to mod-4 / mod-256 dispatch strides.
    {
        const int k = id % 3;
        if (k == 1) {
            __builtin_amdgcn_s_sleep(10);               // ~640 cyc
        } else if (k == 2) {
            __builtin_amdgcn_s_sleep(10);
            __builtin_amdgcn_s_sleep(10);               // ~1280 cyc
        }
    }

    const float4* w4 = reinterpret_cast<const float4*>(cw4);

    float acc[28];
    #pragma unroll
    for (int i = 0; i < 28; ++i) acc[i] = 0.f;

    #pragma unroll 1
    for (int c = 0; c < 4; ++c) {
        const float* xc = x + b * 2400 + c * 600 + 7 * p0;  // uniform -> s_load
        float xw[46];
        #pragma unroll
        for (int j = 0; j < 46; ++j) xw[j] = xc[j];
        #pragma unroll
        for (int kq = 0; kq < 5; ++kq) {
            const float4 wv4 = w4[(c * 5 + kq) * 300 + nc]; // 4 k's, coalesced
            const int ni = (kq == 4) ? 3 : 4;               // k<19
            #pragma unroll
            for (int i = 0; i < ni; ++i) {
                const int k = 4 * kq + i;
                const float wvv = (i == 0) ? wv4.x : (i == 1) ? wv4.y
                                : (i == 2) ? wv4.z : wv4.w;
                #pragma unroll
                for (int p = 0; p < 4; ++p)
                    #pragma unroll
                    for (int q = 0; q < 7; ++q)
                        acc[p * 7 + q] = fmaf(xw[7 * p + q + k], wvv,
                                              acc[p * 7 + q]);
            }
        }
    }

    const float A1 = g1[nc] * rsqrtf(v1[nc] + EPS_);
    const float B1 = fmaf(A1, conv_b[nc] - m1[nc], b1[nc]);
    if (n < 300) {
        float* op = pooled + ((size_t)n * 83 + p0) * 128 + b;
        #pragma unroll
        for (int p = 0; p < 4; ++p) {
            float mx = -INFINITY;           // exp monotone: max before exp
            #pragma unroll
            for (int q = 0; q < 7; ++q)
                mx = fmaxf(mx, fmaf(A1, acc[p * 7 + q], B1));
            op[p * 128] = __expf(mx);
        }
    }
}

// ---------------------------------------------------------------------------
// kB: fc1(K=83) + bn2 + relu + fc2 partial.  R16 structure, R25: unroll 8
// on the pv loop (deeper load pipeline; per-acc FMA order unchanged).
// block = (n, b-half, h-half), grid 1200 x 256 -> 4.7 waves/SIMD;
// sW[83][60] staging; fc2 partials to sp; kC absorbs fc2b+bn3+relu.
// ---------------------------------------------------------------------------
__global__ __launch_bounds__(256) void kB(
        const float* __restrict__ pooled,   // [300][83][128]
        const float* __restrict__ fc1w,     // [300][100][83]
        const float* __restrict__ fc1b,     // [300][100]
        const float* __restrict__ g2, const float* __restrict__ b2,
        const float* __restrict__ m2, const float* __restrict__ v2,
        const float* __restrict__ fc2w,     // [300][100]
        float* __restrict__ sp)             // [2][300][128] fc2 partials
{
    __shared__ float sW[83 * 60];           // 19.9 KB
    __shared__ float sRed[4][64];
    const int id  = blockIdx.x;             // 0..1199
    const int n   = id >> 2;
    const int rem = id & 3;
    const int bh  = rem >> 1;
    const int hq  = rem & 1;                // h-half: h in [hq*50, hq*50+50)
    const int tid = threadIdx.x;

    {   // stage this h-half: coalesced reads; stride-60 writes (8-way, ~free)
        const float* src = fc1w + (size_t)n * 8300 + hq * 50 * 83;
        for (int i = tid; i < 4150; i += 256) {
            const int h = i / 83, p = i - h * 83;
            sW[p * 60 + h] = src[i];
        }
        for (int i = tid; i < 830; i += 256) {   // zero pad h'=50..59
            const int p = i / 10, h = 50 + (i - p * 10);
            sW[p * 60 + h] = 0.f;
        }
    }
    __syncthreads();

    const int lane = tid & 63;
    const int wv   = __builtin_amdgcn_readfirstlane(tid >> 6);  // 0..3
    const int h0   = wv * 13;               // local: 0,13,26,39
    const int nh   = (wv < 3) ? 13 : 11;    // 13*3+11 = 50
    const int bb   = bh * 64 + lane;

    const float* pp = pooled + (size_t)n * 83 * 128 + bb;

    float acc[13];
    #pragma unroll
    for (int j = 0; j < 13; ++j) acc[j] = 0.f;

    #pragma unroll 8
    for (int p = 0; p < 83; ++p) {
        const float pv = pp[p * 128];       // coalesced 256B
        const float* wrow = sW + p * 60 + h0;
        #pragma unroll
        for (int j = 0; j < 13; ++j)        // broadcast b32 reads
            acc[j] = fmaf(wrow[j], pv, acc[j]);
    }

    // bn2 + relu + fc2 partial over this wave's real h's (params uniform)
    const int hbase = n * 100 + hq * 50 + h0;
    float part = 0.f;
    for (int j = 0; j < nh; ++j) {
        const int hi = hbase + j;
        const float A2 = g2[hi] * rsqrtf(v2[hi] + EPS_);
        const float C2 = fmaf(A2, fc1b[hi] - m2[hi], b2[hi]);
        part = fmaf(fmaxf(fmaf(A2, acc[j], C2), 0.f), fc2w[hi], part);
    }
    sRed[wv][lane] = part;
    __syncthreads();

    if (tid < 64) {
        const float s = sRed[0][tid] + sRed[1][tid] + sRed[2][tid] + sRed[3][tid];
        sp[((size_t)hq * 300 + n) * 128 + bh * 64 + tid] = s;
    }
}

// ---------------------------------------------------------------------------
// kC: combine fc2 partials + fc2b + bn3 + relu, then final [300]x[2] matmul.
// ---------------------------------------------------------------------------
__global__ __launch_bounds__(64) void kC(
        const float* __restrict__ sp,       // [2][300][128]
        const float* __restrict__ fc2b,
        const float* __restrict__ g3, const float* __restrict__ b3,
        const float* __restrict__ m3, const float* __restrict__ v3,
        const float* __restrict__ fw,       // [2][300]
        const float* __restrict__ fb,
        float* __restrict__ out)            // [128][2]
{
    const int b = blockIdx.x, t = threadIdx.x;
    float a0 = 0.f, a1 = 0.f;
    for (int nn = t; nn < 300; nn += 64) {
        const float s = sp[nn * 128 + b] + sp[(300 + nn) * 128 + b] + fc2b[nn];
        const float A3 = g3[nn] * rsqrtf(v3[nn] + EPS_);
        const float z = fmaxf(fmaf(A3, s - m3[nn], b3[nn]), 0.f);
        a0 = fmaf(z, fw[nn], a0);
        a1 = fmaf(z, fw[300 + nn], a1);
    }
    #pragma unroll
    for (int off = 32; off > 0; off >>= 1) {
        a0 += __shfl_xor(a0, off, 64);
        a1 += __shfl_xor(a1, off, 64);
    }
    if (t == 0) {
        out[b * 2 + 0] = a0 + fb[0];
        out[b * 2 + 1] = a1 + fb[1];
    }
}

extern "C" void kernel_launch(void* const* d_in, const int* in_sizes, int n_in,
                              void* d_out, int out_size, void* d_ws, size_t ws_size,
                              hipStream_t stream) {
    const float* x      = (const float*)d_in[0];
    const float* conv_w = (const float*)d_in[1];
    const float* conv_b = (const float*)d_in[2];
    const float* g1 = (const float*)d_in[3];
    const float* b1 = (const float*)d_in[4];
    const float* m1 = (const float*)d_in[5];
    const float* v1 = (const float*)d_in[6];
    const float* fc1_w = (const float*)d_in[7];
    const float* fc1_b = (const float*)d_in[8];
    const float* g2 = (const float*)d_in[9];
    const float* b2 = (const float*)d_in[10];
    const float* m2 = (const float*)d_in[11];
    const float* v2 = (const float*)d_in[12];
    const float* fc2_w = (const float*)d_in[13];
    const float* fc2_b = (const float*)d_in[14];
    const float* g3 = (const float*)d_in[15];
    const float* b3 = (const float*)d_in[16];
    const float* m3 = (const float*)d_in[17];
    const float* v3 = (const float*)d_in[18];
    const float* fw = (const float*)d_in[19];
    const float* fb = (const float*)d_in[20];
    float* out = (float*)d_out;

    float* pooled = (float*)d_ws;                        // 300*83*128 = 3187200
    float* sp     = pooled + (size_t)300 * 83 * 128;     // 2*300*128  = 76800
    float* cw4    = sp + 76800;                          // 4*5*300*4  = 24000
    // total ws: ~13.2 MB

    kP<<<20, 256, 0, stream>>>(conv_w, cw4);
    kA<<<128 * 56, 128, 0, stream>>>(x, cw4, conv_b, g1, b1, m1, v1, pooled);
    kB<<<1200, 256, 0, stream>>>(pooled, fc1_w, fc1_b, g2, b2, m2, v2,
                                 fc2_w, sp);
    kC<<<128, 64, 0, stream>>>(sp, fc2_b, g3, b3, m3, v3, fw, fb, out);
}